// Round 13
// baseline (622.379 us; speedup 1.0000x reference)
//
#include <hip/hip_runtime.h>
#include <hip/hip_bf16.h>

typedef unsigned short u16;
typedef __attribute__((ext_vector_type(8))) short short8;
typedef __attribute__((ext_vector_type(4))) float f32x4;

#define T_STEPS 10
#define NB 8
#define HH 64
#define WW 64
#define FF 64
#define NGATE 256
#define HP 66
#define PIX (NB*HH*WW)          // 32768

// dynamic LDS layout (u16 offsets): A 8 rows x 528 chunks x 8 u16
#define SA_U16 33792            // 67584 B
#define SB_U16 16384            // 32768 B per B buffer
#define SMEM_BYTES (SA_U16*2 + 2*SB_U16*2 + 4*(WW+2)*4)   // 134176

__device__ __forceinline__ u16 f2bf(float f) {
    unsigned u = __float_as_uint(f);
    u += 0x7FFF + ((u >> 16) & 1);   // round-to-nearest-even
    return (u16)(u >> 16);
}
__device__ __forceinline__ float hsig(float x) {
    return fminf(fmaxf(0.2f * x + 0.5f, 0.0f), 1.0f);
}
__device__ __forceinline__ float ftanh(float x) {
    float e = __expf(2.0f * x);
    return 1.0f - 2.0f / (e + 1.0f);
}
__device__ __forceinline__ void gll16(const void* g, void* l) {
    __builtin_amdgcn_global_load_lds(
        (const __attribute__((address_space(1))) unsigned*)g,
        (__attribute__((address_space(3))) unsigned*)l, 16, 0, 0);
}

// Build B in MFMA-fragment-stream order, bf16:
//   stream[kc][fq][ks][g][lane][e]; value = W[kc*64+ks*32+quad*8+e][g*64+fq*16+l15]
__global__ void wtrans_kernel(const float* __restrict__ W0,
                              const float* __restrict__ W1,
                              u16* __restrict__ BS, int K) {
    int total = (K >> 6) << 14;
    for (int o = blockIdx.x * blockDim.x + threadIdx.x; o < total;
         o += gridDim.x * blockDim.x) {
        int e = o & 7, lane = (o >> 3) & 63, g = (o >> 9) & 3;
        int ks = (o >> 11) & 1, fq = (o >> 12) & 3, kc = o >> 14;
        int quad = lane >> 4, l15 = lane & 15;
        int n = g * 64 + fq * 16 + l15;
        int k = kc * 64 + ks * 32 + quad * 8 + e;
        float v = (k < 576) ? W0[k * NGATE + n] : W1[(k - 576) * NGATE + n];
        BS[o] = f2bf(v);
    }
}

// LSTM gate epilogue for one role, one row (lane-local: f = fq*16+l15).
__device__ __forceinline__ void epilogue(const f32x4 (&acc)[4][4],
                                         const float* __restrict__ bias,
                                         float* __restrict__ cbuf,
                                         u16* __restrict__ hout,
                                         float* __restrict__ outh,
                                         float* __restrict__ outc, int wo,
                                         int withx, const float* xsr,
                                         const float* __restrict__ k0w,
                                         int b, int y, int pxb,
                                         int fq, int quad, int l15) {
    int f = fq * 16 + l15;
    float bi = bias[f], bff = bias[64 + f], bg = bias[128 + f], bo = bias[192 + f];
    float wk[4][9];
    if (withx) {
#pragma unroll
        for (int g = 0; g < 4; ++g)
#pragma unroll
            for (int tau = 0; tau < 9; ++tau)
                wk[g][tau] = k0w[tau * NGATE + g * 64 + f];
    }
#pragma unroll
    for (int mt = 0; mt < 4; ++mt) {
#pragma unroll
        for (int r = 0; r < 4; ++r) {
            int xcol = mt * 16 + quad * 4 + r;      // pixel x within the row
            size_t p = (size_t)pxb * 64 + xcol;     // global pixel
            float zi = acc[mt][0][r] + bi;
            float zf = acc[mt][1][r] + bff;
            float zg = acc[mt][2][r] + bg;
            float zo = acc[mt][3][r] + bo;
            if (withx) {       // fused layer-0 input conv, fp32 exact
#pragma unroll
                for (int tau = 0; tau < 9; ++tau) {
                    float xv = xsr[(tau / 3) * (WW + 2) + xcol + tau % 3];
                    zi += xv * wk[0][tau];
                    zf += xv * wk[1][tau];
                    zg += xv * wk[2][tau];
                    zo += xv * wk[3][tau];
                }
            }
            float cold = cbuf[p * FF + f];
            float cn = hsig(zf) * cold + hsig(zi) * ftanh(zg);
            float hn = hsig(zo) * ftanh(cn);
            cbuf[p * FF + f] = cn;
            hout[(((size_t)(b * HP + y + 1)) * HP + (xcol + 1)) * FF + f] = f2bf(hn);
            if (wo) { outh[p * FF + f] = hn; outc[p * FF + f] = cn; }
        }
    }
}

// Fused dual-layer ConvLSTM tick. B-VIA-LDS design (r12 post-mortem: the
// pinned 21-24% MfmaUtil across 12 structures is the per-CU L1 fill-rate
// wall for flat loads: measured 13.5-15.3 B/cyc/CU in both r6 and r12 =
// one 64B line per ~4cyc; it caps AI=64FLOP/B at ~25% MFMA).
// global_load_lds BYPASSES L1 (m97 sustains ~40 B/cyc/CU), so B now goes
// gll -> double-buffered LDS. 512-thread blocks cover 2 rows (8 waves =
// 2 rowgroups x 4 fq): each 32KB B kc-chunk staged once serves both rows.
// Per kc: issue 4 glls/thread for B(kc+1) -> compute (A + B from LDS) ->
// vmcnt(0)+barrier (staged loads had the whole compute to land).
// 256 uniform blocks (both phases per block), 1/CU, LDS ~131KB dynamic.
__global__ __launch_bounds__(512, 2)
void fused_step_kernel(const u16* __restrict__ h0_prev, u16* __restrict__ h0_new,
                       const u16* __restrict__ h1_prev, u16* __restrict__ h1_new,
                       const u16* __restrict__ B0S, const u16* __restrict__ B1S,
                       const float* __restrict__ x, const float* __restrict__ k0w,
                       const float* __restrict__ b0, const float* __restrict__ b1,
                       float* __restrict__ c0, float* __restrict__ c1,
                       float* __restrict__ oh0, float* __restrict__ oc0,
                       float* __restrict__ oh1, float* __restrict__ oc1,
                       int u) {
    extern __shared__ __align__(16) char smem[];
    u16* sA  = (u16*)smem;
    u16* sB0 = sA + SA_U16;
    u16* sB1 = sB0 + SB_U16;
    float* xs = (float*)(smem + (SA_U16 + 2 * SB_U16) * 2);  // [4][WW+2]

    int blk = blockIdx.x;
    int b = blk & 7;                 // batch == XCD (blockIdx % 8 round-robin)
    int y0 = (blk >> 3) << 1;        // first of two image rows: 0,2,..,62
    int tid = threadIdx.x;
    int w = tid >> 6, lane = tid & 63;
    int rw = w >> 2, fq = w & 3;     // row-group 0/1, gate quadrant
    int quad = lane >> 4, l15 = lane & 15;
    int do0 = (u < T_STEPS);         // layer-0 step u
    int do1 = (u > 0);               // layer-1 step u-1

    if (do0 && tid < 4 * (WW + 2)) {
        int dyi = tid / (WW + 2), xx = tid - dyi * (WW + 2);
        int yy = y0 + dyi - 1, col = xx - 1;
        float v = 0.0f;
        if (yy >= 0 && yy < HH && col >= 0 && col < WW)
            v = x[(((size_t)b * T_STEPS + u) * HH + yy) * WW + col];
        xs[dyi * (WW + 2) + xx] = v;
    }

    // ---- A staging: padded rows y0..y0+3 of h0 (+h1 if do1), rows-once ----
    {
        int nstA = do1 ? 4224 : 2112;        // 16B chunks
        for (int i = tid; i < nstA; i += 512) {
            int sel = i >= 2112;
            int q = i - (sel ? 2112 : 0);
            int r = q / 528, qr = q - r * 528;
            int p = qr >> 3, cb = (qr & 7) ^ (p & 7);
            const u16* src = sel ? h1_prev : h0_prev;
            gll16(src + (((size_t)(b * HP + y0 + r)) * HP + p) * FF + cb * 8,
                  sA + (size_t)i * 8);
        }
    }
    // ---- B prologue: first active step's 32KB chunk -> sB0 ----
    {
        const u16* bsrc = do0 ? B0S : B1S;   // step gs0's chunk 0
#pragma unroll
        for (int j = 0; j < 4; ++j) {
            int idx = tid + j * 512;
            gll16(bsrc + (size_t)idx * 8, sB0 + (size_t)idx * 8);
        }
    }
    asm volatile("s_waitcnt vmcnt(0) lgkmcnt(0)\n\ts_barrier" ::: "memory");

    f32x4 acc[4][4];
#pragma unroll
    for (int mt = 0; mt < 4; ++mt)
#pragma unroll
        for (int g = 0; g < 4; ++g)
            acc[mt][g] = (f32x4){0.f, 0.f, 0.f, 0.f};

    // global step gs: 0..8 = layer-0 kc; 9..26 = layer-1 kc 0..17.
    // A row index: srIdx = rw + (gs%9)/3 + (gs>=18 ? 4 : 0).
    int gs0 = do0 ? 0 : 9;
    int gsEnd = do1 ? 27 : 9;
    int buf = 0, dx = 0, srl = 0;
    for (int gs = gs0; gs < gsEnd; ++gs) {
        // stage next step's B chunk into the other buffer (issue-early)
        if (gs + 1 < gsEnd) {
            int n = gs + 1;
            const u16* bn = (n < 9) ? B0S + ((size_t)n << 14)
                                    : B1S + ((size_t)(n - 9) << 14);
            u16* dst = buf ? sB0 : sB1;
#pragma unroll
            for (int j = 0; j < 4; ++j) {
                int idx = tid + j * 512;
                gll16(bn + (size_t)idx * 8, dst + (size_t)idx * 8);
            }
        }
        // compute on sB[buf] + staged A rows
        {
            const u16* sb = buf ? sB1 : sB0;
            int srIdx = rw + srl + ((gs >= 18) ? 4 : 0);
            int cc = l15 + dx, sw = cc & 7;
            const u16* abase = sA + srIdx * 4224 + cc * 64;
#pragma unroll
            for (int ks = 0; ks < 2; ++ks) {
                short8 bF[4], aF[4];
                const u16* bp = sb + ((fq << 12) | (ks << 11)) + lane * 8;
#pragma unroll
                for (int g = 0; g < 4; ++g)
                    bF[g] = *(const short8*)(bp + (g << 9));
                int so = ((((ks << 2) | quad) ^ sw) << 3);
#pragma unroll
                for (int mt = 0; mt < 4; ++mt)
                    aF[mt] = *(const short8*)(abase + so + mt * 1024);
#pragma unroll
                for (int mt = 0; mt < 4; ++mt)
#pragma unroll
                    for (int g = 0; g < 4; ++g)
                        acc[mt][g] = __builtin_amdgcn_mfma_f32_16x16x32_bf16(
                            aF[mt], bF[g], acc[mt][g], 0, 0, 0);
            }
        }
        // next buffer resident; all waves done reading current buffer.
        asm volatile("s_waitcnt vmcnt(0) lgkmcnt(0)\n\ts_barrier" ::: "memory");
        buf ^= 1;
        ++dx;
        if (dx == 3) { dx = 0; ++srl; if (srl == 3) srl = 0; }
        // phase boundary: layer-0 epilogue + acc reset (wave-local, no barrier)
        if (gs == 8 && do0) {
            epilogue(acc, b0, c0, h0_new, oh0, oc0, u == T_STEPS - 1,
                     1, xs + rw * (WW + 2), k0w, b, y0 + rw, b * 64 + y0 + rw,
                     fq, quad, l15);
#pragma unroll
            for (int mt = 0; mt < 4; ++mt)
#pragma unroll
                for (int g = 0; g < 4; ++g)
                    acc[mt][g] = (f32x4){0.f, 0.f, 0.f, 0.f};
        }
    }
    if (do1)
        epilogue(acc, b1, c1, h1_new, oh1, oc1, u == T_STEPS,
                 0, xs, k0w, b, y0 + rw, b * 64 + y0 + rw, fq, quad, l15);
}

extern "C" void kernel_launch(void* const* d_in, const int* in_sizes, int n_in,
                              void* d_out, int out_size, void* d_ws, size_t ws_size,
                              hipStream_t stream) {
    const float* x   = (const float*)d_in[0];
    const float* k0  = (const float*)d_in[1];
    const float* rk0 = (const float*)d_in[2];
    const float* b0  = (const float*)d_in[3];
    const float* k1  = (const float*)d_in[4];
    const float* rk1 = (const float*)d_in[5];
    const float* b1  = (const float*)d_in[6];
    float* out = (float*)d_out;

    char* ws = (char*)d_ws;
    const size_t HPAD_BYTES = (size_t)NB * HP * HP * FF * 2;  // 4,460,544
    const size_t C_BYTES    = (size_t)PIX * FF * 4;           // 8,388,608

    u16* h0p[2]; u16* h1p[2];
    h0p[0] = (u16*)(ws);
    h0p[1] = (u16*)(ws + HPAD_BYTES);
    h1p[0] = (u16*)(ws + 2 * HPAD_BYTES);
    h1p[1] = (u16*)(ws + 3 * HPAD_BYTES);
    float* c0 = (float*)(ws + 4 * HPAD_BYTES);
    float* c1 = (float*)(ws + 4 * HPAD_BYTES + C_BYTES);
    u16* B0S  = (u16*)(ws + 4 * HPAD_BYTES + 2 * C_BYTES);
    u16* B1S  = (u16*)(ws + 4 * HPAD_BYTES + 2 * C_BYTES + (size_t)9 * 16384 * 2);

    // allow >64KB dynamic LDS for the fused kernel (idempotent host call)
    hipFuncSetAttribute((const void*)fused_step_kernel,
                        hipFuncAttributeMaxDynamicSharedMemorySize, SMEM_BYTES);

    // Zero h (incl. halo == SAME padding) and c states; ws is poisoned 0xAA.
    hipMemsetAsync(ws, 0, 4 * HPAD_BYTES + 2 * C_BYTES, stream);

    wtrans_kernel<<<512, 256, 0, stream>>>(rk0, rk0, B0S, 576);
    wtrans_kernel<<<512, 256, 0, stream>>>(k1, rk1, B1S, 1152);

    float* oh0 = out;
    float* oc0 = out + (size_t)PIX * FF;
    float* oh1 = out + 2 * (size_t)PIX * FF;
    float* oc1 = out + 3 * (size_t)PIX * FF;

    // Tick u: layer-0 computes step u (reads h0[u-1] -> writes h0[u]);
    //         layer-1 computes step u-1 (reads h0[u-1], h1[u-2] -> h1[u-1]).
    for (int u = 0; u <= T_STEPS; ++u) {
        const u16* h0_prev = h0p[(u + 1) & 1];
        u16*       h0_new  = h0p[u & 1];
        const u16* h1_prev = h1p[u & 1];
        u16*       h1_new  = h1p[(u + 1) & 1];
        fused_step_kernel<<<256, 512, SMEM_BYTES, stream>>>(
            h0_prev, h0_new, h1_prev, h1_new, B0S, B1S,
            x, k0, b0, b1, c0, c1, oh0, oc0, oh1, oc1, u);
    }
}

// Round 14
// 477.508 us; speedup vs baseline: 1.3034x; 1.3034x over previous
//
#include <hip/hip_runtime.h>
#include <hip/hip_bf16.h>

typedef unsigned short u16;
typedef __attribute__((ext_vector_type(8))) short short8;
typedef __attribute__((ext_vector_type(4))) float f32x4;

#define T_STEPS 10
#define NB 8
#define HH 64
#define WW 64
#define FF 64
#define NGATE 256
#define HP 66
#define PIX (NB*HH*WW)          // 32768

__device__ __forceinline__ u16 f2bf(float f) {
    unsigned u = __float_as_uint(f);
    u += 0x7FFF + ((u >> 16) & 1);   // round-to-nearest-even
    return (u16)(u >> 16);
}
__device__ __forceinline__ float hsig(float x) {
    return fminf(fmaxf(0.2f * x + 0.5f, 0.0f), 1.0f);
}
__device__ __forceinline__ float ftanh(float x) {
    float e = __expf(2.0f * x);
    return 1.0f - 2.0f / (e + 1.0f);
}
__device__ __forceinline__ void gll16(const void* g, void* l) {
    __builtin_amdgcn_global_load_lds(
        (const __attribute__((address_space(1))) unsigned*)g,
        (__attribute__((address_space(3))) unsigned*)l, 16, 0, 0);
}

// Build B in MFMA-fragment-stream order, bf16:
//   stream[kc][fq][ks][g][lane][e]; value = W[kc*64+ks*32+quad*8+e][g*64+fq*16+l15]
__global__ void wtrans_kernel(const float* __restrict__ W0,
                              const float* __restrict__ W1,
                              u16* __restrict__ BS, int K) {
    int total = (K >> 6) << 14;
    for (int o = blockIdx.x * blockDim.x + threadIdx.x; o < total;
         o += gridDim.x * blockDim.x) {
        int e = o & 7, lane = (o >> 3) & 63, g = (o >> 9) & 3;
        int ks = (o >> 11) & 1, fq = (o >> 12) & 3, kc = o >> 14;
        int quad = lane >> 4, l15 = lane & 15;
        int n = g * 64 + fq * 16 + l15;
        int k = kc * 64 + ks * 32 + quad * 8 + e;
        float v = (k < 576) ? W0[k * NGATE + n] : W1[(k - 576) * NGATE + n];
        BS[o] = f2bf(v);
    }
}

__device__ __forceinline__ void stageA(const u16* __restrict__ h0_prev,
                                       const u16* __restrict__ h1_prev,
                                       int kcs, int b, int y,
                                       int p0, int cb0, int p1, int cb1,
                                       u16* ldst0, u16* ldst1) {
    int tau = (kcs < 9) ? kcs : kcs - 9;
    const u16* src = (kcs < 9) ? h0_prev : h1_prev;
    int dy = tau / 3 - 1, dx = tau % 3 - 1;
    const u16* rbase = src + (((size_t)(b * HP + y + dy + 1)) * HP + dx + 1) * FF;
    gll16(rbase + (size_t)p0 * FF + cb0 * 8, ldst0);
    gll16(rbase + (size_t)p1 * FF + cb1 * 8, ldst1);
}

// Fused dual-layer ConvLSTM tick; XCD-local batches (batch = blockIdx & 7).
// Best-measured structure (483.5us): M=64, 1024 blocks, 2 role-0 + 2 role-1
// per CU, triple-buffered LDS A via global_load_lds with distance-2 prefetch
// kept in flight ACROSS barriers (raw s_barrier + vmcnt(2)); B direct from
// the XCD-L2-resident fragment stream.
// 13-round conclusion: this sits on the per-CU B-delivery wall (~18 B/cyc
// L1-miss fill rate x AI 65 FLOP/B -> ~40us/dispatch); deeper pipelines,
// barrier removal, occupancy shaping, and L1-bypass all failed to beat it.
__global__ __launch_bounds__(256, 4)
void fused_step_kernel(const u16* __restrict__ h0_prev, u16* __restrict__ h0_new,
                       const u16* __restrict__ h1_prev, u16* __restrict__ h1_new,
                       const u16* __restrict__ B0S, const u16* __restrict__ B1S,
                       const float* __restrict__ x, const float* __restrict__ k0w,
                       const float* __restrict__ b0, const float* __restrict__ b1,
                       float* __restrict__ c0, float* __restrict__ c1,
                       float* __restrict__ oh0, float* __restrict__ oc0,
                       float* __restrict__ oh1, float* __restrict__ oc1,
                       int u) {
    int blk = blockIdx.x;
    int b = blk & 7;                 // batch == XCD (blockIdx % 8 round-robin)
    int k = blk >> 3;                // XCD-local index 0..127 (-> CU k%32)
    int role = (k >> 5) & 1;         // 0: layer-0 step u; 1: layer-1 step u-1
    int y = (k & 31) | ((k >> 6) << 5);   // image row 0..63
    int pxb = b * 64 + y;
    if (role == 0 && u >= T_STEPS) return;
    if (role == 1 && u == 0) return;

    // A tile: 512 16B-chunks; chunk q holds px=q>>3, ch-block (q&7)^(px&7).
    __shared__ __align__(16) u16 sA3[3][4096];
    __shared__ float xs[3][WW + 2];

    int tid = threadIdx.x;
    int lane = tid & 63, fq = tid >> 6;
    int quad = lane >> 4, l15 = lane & 15;

    const u16* BS = role ? B1S : B0S;
    int nch = role ? 18 : 9;

    if (role == 0 && tid < 3 * (WW + 2)) {
        int dyi = tid / (WW + 2), xx = tid - dyi * (WW + 2);
        int yy = y + dyi - 1, col = xx - 1;
        float v = 0.0f;
        if (yy >= 0 && yy < HH && col >= 0 && col < WW)
            v = x[(((size_t)b * T_STEPS + u) * HH + yy) * WW + col];
        xs[dyi][xx] = v;
    }

    // Per-thread staging chunks: q0=tid, q1=256+tid (lds dst = base+tid*16,
    // wave-uniform base + lane*16 as global_load_lds requires).
    int q0 = tid, q1 = 256 + tid;
    int p0 = q0 >> 3, cb0 = (q0 & 7) ^ (p0 & 7);
    int p1 = q1 >> 3, cb1 = (q1 & 7) ^ (p1 & 7);

    f32x4 acc[4][4];
#pragma unroll
    for (int mt = 0; mt < 4; ++mt)
#pragma unroll
        for (int g = 0; g < 4; ++g)
            acc[mt][g] = (f32x4){0.f, 0.f, 0.f, 0.f};

    // ---- pipeline prologue ----
    stageA(h0_prev, h1_prev, 0, b, y, p0, cb0, p1, cb1,
           &sA3[0][(size_t)q0 * 8], &sA3[0][(size_t)q1 * 8]);
    asm volatile("s_waitcnt vmcnt(0) lgkmcnt(0)\n\ts_barrier" ::: "memory");
    if (nch > 1)
        stageA(h0_prev, h1_prev, 1, b, y, p0, cb0, p1, cb1,
               &sA3[1][(size_t)q0 * 8], &sA3[1][(size_t)q1 * 8]);

    int sx = l15 & 7;
    int cur = 0;
    for (int kc = 0; kc < nch; ++kc) {
        // compute on buffer cur (gll(kc) drained by previous barrier)
#pragma unroll
        for (int ks = 0; ks < 2; ++ks) {
            short8 bF[4];
            const u16* bp = BS + (((size_t)kc << 14) | (fq << 12) | (ks << 11))
                          + lane * 8;
#pragma unroll
            for (int g = 0; g < 4; ++g)
                bF[g] = *(const short8*)(bp + ((size_t)g << 9));
            short8 aF[4];
#pragma unroll
            for (int mt = 0; mt < 4; ++mt) {
                int px = mt * 16 + l15;
                int chunk = px * 8 + ((ks * 4 + quad) ^ sx);
                aF[mt] = *(const short8*)&sA3[cur][(size_t)chunk * 8];
            }
#pragma unroll
            for (int mt = 0; mt < 4; ++mt)
#pragma unroll
                for (int g = 0; g < 4; ++g)
                    acc[mt][g] = __builtin_amdgcn_mfma_f32_16x16x32_bf16(
                        aF[mt], bF[g], acc[mt][g], 0, 0, 0);
        }
        // distance-2 prefetch; dummy re-stage of an unread buffer in the tail
        // keeps the per-iteration vmcnt count uniform (always 2 glls issued).
        {
            int ksrc = (kc + 2 < nch) ? kc + 2 : kc;
            int bdst = (cur + 2 >= 3) ? cur - 1 : cur + 2;
            stageA(h0_prev, h1_prev, ksrc, b, y, p0, cb0, p1, cb1,
                   &sA3[bdst][(size_t)q0 * 8], &sA3[bdst][(size_t)q1 * 8]);
        }
        // drain gll(kc+1) (+ all B loads); keep gll(kc+2) in flight.
        asm volatile("s_waitcnt vmcnt(2) lgkmcnt(0)\n\ts_barrier" ::: "memory");
        cur = (cur == 2) ? 0 : cur + 1;
    }

    // ---- epilogue: LSTM gate update (lane-local: f = fq*16+l15) ----
    const float* bias = role ? b1 : b0;
    float* cbuf = role ? c1 : c0;
    u16* hout = role ? h1_new : h0_new;
    int wo = role ? (u == T_STEPS) : (u == T_STEPS - 1);
    float* outh = role ? oh1 : oh0;
    float* outc = role ? oc1 : oc0;

    int f = fq * 16 + l15;
    float bi = bias[f], bff = bias[64 + f], bg = bias[128 + f], bo = bias[192 + f];
    float wk[4][9];
    if (role == 0) {
#pragma unroll
        for (int g = 0; g < 4; ++g)
#pragma unroll
            for (int tau = 0; tau < 9; ++tau)
                wk[g][tau] = k0w[tau * NGATE + g * 64 + f];
    }
#pragma unroll
    for (int mt = 0; mt < 4; ++mt) {
#pragma unroll
        for (int r = 0; r < 4; ++r) {
            int xcol = mt * 16 + quad * 4 + r;      // pixel x within the row
            size_t p = (size_t)pxb * 64 + xcol;     // global pixel
            float zi = acc[mt][0][r] + bi;
            float zf = acc[mt][1][r] + bff;
            float zg = acc[mt][2][r] + bg;
            float zo = acc[mt][3][r] + bo;
            if (role == 0) {   // fused layer-0 input conv, fp32 exact
#pragma unroll
                for (int tau = 0; tau < 9; ++tau) {
                    float xv = xs[tau / 3][xcol + tau % 3];
                    zi += xv * wk[0][tau];
                    zf += xv * wk[1][tau];
                    zg += xv * wk[2][tau];
                    zo += xv * wk[3][tau];
                }
            }
            float cold = cbuf[p * FF + f];
            float cn = hsig(zf) * cold + hsig(zi) * ftanh(zg);
            float hn = hsig(zo) * ftanh(cn);
            cbuf[p * FF + f] = cn;
            hout[(((size_t)(b * HP + y + 1)) * HP + (xcol + 1)) * FF + f] = f2bf(hn);
            if (wo) { outh[p * FF + f] = hn; outc[p * FF + f] = cn; }
        }
    }
}

extern "C" void kernel_launch(void* const* d_in, const int* in_sizes, int n_in,
                              void* d_out, int out_size, void* d_ws, size_t ws_size,
                              hipStream_t stream) {
    const float* x   = (const float*)d_in[0];
    const float* k0  = (const float*)d_in[1];
    const float* rk0 = (const float*)d_in[2];
    const float* b0  = (const float*)d_in[3];
    const float* k1  = (const float*)d_in[4];
    const float* rk1 = (const float*)d_in[5];
    const float* b1  = (const float*)d_in[6];
    float* out = (float*)d_out;

    char* ws = (char*)d_ws;
    const size_t HPAD_BYTES = (size_t)NB * HP * HP * FF * 2;  // 4,460,544
    const size_t C_BYTES    = (size_t)PIX * FF * 4;           // 8,388,608

    u16* h0p[2]; u16* h1p[2];
    h0p[0] = (u16*)(ws);
    h0p[1] = (u16*)(ws + HPAD_BYTES);
    h1p[0] = (u16*)(ws + 2 * HPAD_BYTES);
    h1p[1] = (u16*)(ws + 3 * HPAD_BYTES);
    float* c0 = (float*)(ws + 4 * HPAD_BYTES);
    float* c1 = (float*)(ws + 4 * HPAD_BYTES + C_BYTES);
    u16* B0S  = (u16*)(ws + 4 * HPAD_BYTES + 2 * C_BYTES);
    u16* B1S  = (u16*)(ws + 4 * HPAD_BYTES + 2 * C_BYTES + (size_t)9 * 16384 * 2);

    // Zero h (incl. halo == SAME padding) and c states; ws is poisoned 0xAA.
    hipMemsetAsync(ws, 0, 4 * HPAD_BYTES + 2 * C_BYTES, stream);

    wtrans_kernel<<<512, 256, 0, stream>>>(rk0, rk0, B0S, 576);
    wtrans_kernel<<<512, 256, 0, stream>>>(k1, rk1, B1S, 1152);

    float* oh0 = out;
    float* oc0 = out + (size_t)PIX * FF;
    float* oh1 = out + 2 * (size_t)PIX * FF;
    float* oc1 = out + 3 * (size_t)PIX * FF;

    // Tick u: layer-0 computes step u (reads h0[u-1] -> writes h0[u]);
    //         layer-1 computes step u-1 (reads h0[u-1], h1[u-2] -> h1[u-1]).
    for (int u = 0; u <= T_STEPS; ++u) {
        const u16* h0_prev = h0p[(u + 1) & 1];
        u16*       h0_new  = h0p[u & 1];
        const u16* h1_prev = h1p[u & 1];
        u16*       h1_new  = h1p[(u + 1) & 1];
        fused_step_kernel<<<1024, 256, 0, stream>>>(
            h0_prev, h0_new, h1_prev, h1_new, B0S, B1S,
            x, k0, b0, b1, c0, c1, oh0, oc0, oh1, oc1, u);
    }
}